// Round 9
// baseline (195.073 us; speedup 1.0000x reference)
//
#include <hip/hip_runtime.h>

#define S_LEN 2048
#define D_MODEL 1024
#define NHEAD 16
#define HDIM 64
#define BATCH 2
#define M_ROWS (BATCH * S_LEN)   // 4096
#define N_QKV (3 * D_MODEL)      // 3072
#define QSCALE 0.18033688011112042f  // 0.125 * log2(e)

typedef __attribute__((ext_vector_type(8))) short bf16x8;
typedef __attribute__((ext_vector_type(4))) float f32x4;

static __device__ __forceinline__ unsigned short f2bf(float f) {
  unsigned int u = __float_as_uint(f);
  u += 0x7FFFu + ((u >> 16) & 1u);   // RNE
  return (unsigned short)(u >> 16);
}
// pack two floats to bf16x2
static __device__ __forceinline__ unsigned int pkbf(float a, float b) {
  unsigned int ua = __float_as_uint(a) + 0x8000u;
  unsigned int ub = __float_as_uint(b) + 0x8000u;
  return __builtin_amdgcn_perm(ub, ua, 0x07060302u);
}

// async global->LDS 16B copy; effective LDS dst = wave-uniform base + lane*16
static __device__ __forceinline__ void async_cp16(unsigned short* lds, const unsigned short* g) {
  __builtin_amdgcn_global_load_lds((__attribute__((address_space(1))) void*)g,
                                   (__attribute__((address_space(3))) void*)lds, 16, 0, 0);
}

// ---------------- merged prep: cast x, transpose-cast both weights ----------------
__global__ __launch_bounds__(256) void k_prep(const float* __restrict__ x,
                                              unsigned short* __restrict__ xb,
                                              const float* __restrict__ w_attn,
                                              unsigned short* __restrict__ wqkvT,
                                              const float* __restrict__ w_proj,
                                              unsigned short* __restrict__ wprojT) {
  __shared__ unsigned short T[32][33];
  const int blk = blockIdx.x;
  const int tid = threadIdx.x;
  if (blk < 4096) {
    int i = blk * 256 + tid;
    float4 v = ((const float4*)x)[i];
    ushort4 o;
    o.x = f2bf(v.x); o.y = f2bf(v.y); o.z = f2bf(v.z); o.w = f2bf(v.w);
    ((ushort4*)xb)[i] = o;
    return;
  }
  const float* w;
  unsigned short* wT;
  int bid, Ndim;
  if (blk < 7168) { bid = blk - 4096; w = w_attn; wT = wqkvT; Ndim = N_QKV; }
  else            { bid = blk - 7168; w = w_proj; wT = wprojT; Ndim = D_MODEL; }
  const int nb = Ndim / 32;
  const int n0 = (bid % nb) * 32, k0 = (bid / nb) * 32;
  const int tx = tid & 31, ty = tid >> 5;
#pragma unroll
  for (int j = 0; j < 4; ++j) {
    int r = ty + j * 8;
    T[r][tx] = f2bf(w[(size_t)(k0 + r) * Ndim + n0 + tx]);
  }
  __syncthreads();
#pragma unroll
  for (int j = 0; j < 4; ++j) {
    int r = ty + j * 8;
    wT[(size_t)(n0 + r) * D_MODEL + k0 + tx] = T[tx][r];
  }
}

// ---------------- QKV GEMM: [4096,1024] x [1024,3072] + bias (round-6, unchanged) ----------------
__global__ __launch_bounds__(256) void k_gemm_qkv(const unsigned short* __restrict__ A,
                                                  const unsigned short* __restrict__ Bt,
                                                  const float* __restrict__ bias,
                                                  unsigned short* __restrict__ Qb,
                                                  unsigned short* __restrict__ Kbuf,
                                                  unsigned short* __restrict__ VTb) {
  __shared__ __align__(16) unsigned short As[2][128 * 32];
  __shared__ __align__(16) unsigned short Bs[2][128 * 32];
  const int tid = threadIdx.x;
  const int wid = tid >> 6, lane = tid & 63;
  const int lr = lane & 15, lg = lane >> 4;
  const int blk = blockIdx.x;
  const int xcd = blk & 7, idx = blk >> 3;
  const int bm = ((xcd & 3) * 8 + (idx & 7)) * 128;
  const int bn = ((xcd >> 2) * 12 + (idx >> 3)) * 128;
  const int wm = (wid >> 1) * 64, wn = (wid & 1) * 64;
  const int K = D_MODEL;
  const int c0 = tid, c1 = tid + 256;
  const size_t a0o = (size_t)(bm + (c0 >> 2)) * K + (c0 & 3) * 8;
  const size_t a1o = (size_t)(bm + (c1 >> 2)) * K + (c1 & 3) * 8;
  const size_t b0o = (size_t)(bn + (c0 >> 2)) * K + (c0 & 3) * 8;
  const size_t b1o = (size_t)(bn + (c1 >> 2)) * K + (c1 & 3) * 8;

  f32x4 acc[4][4] = {};

  async_cp16(&As[0][c0 * 8], &A[a0o]);
  async_cp16(&As[0][c1 * 8], &A[a1o]);
  async_cp16(&Bs[0][c0 * 8], &Bt[b0o]);
  async_cp16(&Bs[0][c1 * 8], &Bt[b1o]);

  for (int k0 = 0; k0 < K; k0 += 32) {
    const int p = (k0 >> 5) & 1;
    __syncthreads();
    if (k0 + 32 < K) {
      async_cp16(&As[p ^ 1][c0 * 8], &A[a0o + k0 + 32]);
      async_cp16(&As[p ^ 1][c1 * 8], &A[a1o + k0 + 32]);
      async_cp16(&Bs[p ^ 1][c0 * 8], &Bt[b0o + k0 + 32]);
      async_cp16(&Bs[p ^ 1][c1 * 8], &Bt[b1o + k0 + 32]);
    }
    bf16x8 af[4], bfr[4];
#pragma unroll
    for (int i = 0; i < 4; ++i) af[i] = *(const bf16x8*)&As[p][(wm + i * 16 + lr) * 32 + lg * 8];
#pragma unroll
    for (int t = 0; t < 4; ++t) bfr[t] = *(const bf16x8*)&Bs[p][(wn + t * 16 + lr) * 32 + lg * 8];
#pragma unroll
    for (int i = 0; i < 4; ++i)
#pragma unroll
      for (int t = 0; t < 4; ++t)
        acc[i][t] = __builtin_amdgcn_mfma_f32_16x16x32_bf16(af[i], bfr[t], acc[i][t], 0, 0, 0);
  }
#pragma unroll
  for (int i = 0; i < 4; ++i) {
#pragma unroll
    for (int t = 0; t < 4; ++t) {
      int n = bn + wn + t * 16 + lr;
      int part = n >> 10, rem = n & 1023;
      int h = rem >> 6, d = rem & 63;
      float bv = bias[n];
      int row0 = bm + wm + i * 16 + lg * 4;
      int bb = row0 >> 11, s0 = row0 & 2047;
      if (part == 2) {
        ushort4 vv;
        vv.x = f2bf(acc[i][t][0] + bv);
        vv.y = f2bf(acc[i][t][1] + bv);
        vv.z = f2bf(acc[i][t][2] + bv);
        vv.w = f2bf(acc[i][t][3] + bv);
        *(ushort4*)&VTb[(((size_t)(bb << 4) + h) * HDIM + d) * S_LEN + s0] = vv;
      } else {
        unsigned short* dst = (part == 0) ? Qb : Kbuf;
        float sc = (part == 0) ? QSCALE : 1.0f;
#pragma unroll
        for (int r = 0; r < 4; ++r)
          dst[(((size_t)(bb << 4) + h) * S_LEN + (s0 + r)) * HDIM + d] = f2bf((acc[i][t][r] + bv) * sc);
      }
    }
  }
}

// ---------------- Proj GEMM: 128x64 tiles, 512 blocks (2/CU), XCD swizzle ----------------
__global__ __launch_bounds__(256) void k_gemm_proj(const unsigned short* __restrict__ A,
                                                   const unsigned short* __restrict__ Bt,
                                                   const float* __restrict__ bias,
                                                   float* __restrict__ out) {
  __shared__ __align__(16) unsigned short As[2][128 * 32];
  __shared__ __align__(16) unsigned short Bs[2][64 * 32];
  const int tid = threadIdx.x;
  const int wid = tid >> 6, lane = tid & 63;
  const int lr = lane & 15, lg = lane >> 4;
  const int blk = blockIdx.x;
  const int xcd = blk & 7, idx = blk >> 3;          // 64 blocks per XCD
  const int bm = (xcd * 4 + (idx & 3)) * 128;       // 32 m-tiles
  const int bn = (idx >> 2) * 64;                   // 16 n-tiles
  const int wm = (wid >> 1) * 64, wn = (wid & 1) * 32;
  const int K = D_MODEL;
  const int c0 = tid, c1 = tid + 256;
  const size_t a0o = (size_t)(bm + (c0 >> 2)) * K + (c0 & 3) * 8;
  const size_t a1o = (size_t)(bm + (c1 >> 2)) * K + (c1 & 3) * 8;
  const size_t b0o = (size_t)(bn + (c0 >> 2)) * K + (c0 & 3) * 8;

  f32x4 acc[4][2] = {};

  async_cp16(&As[0][c0 * 8], &A[a0o]);
  async_cp16(&As[0][c1 * 8], &A[a1o]);
  async_cp16(&Bs[0][c0 * 8], &Bt[b0o]);

  for (int k0 = 0; k0 < K; k0 += 32) {
    const int p = (k0 >> 5) & 1;
    __syncthreads();
    if (k0 + 32 < K) {
      async_cp16(&As[p ^ 1][c0 * 8], &A[a0o + k0 + 32]);
      async_cp16(&As[p ^ 1][c1 * 8], &A[a1o + k0 + 32]);
      async_cp16(&Bs[p ^ 1][c0 * 8], &Bt[b0o + k0 + 32]);
    }
    bf16x8 af[4], bfr[2];
#pragma unroll
    for (int i = 0; i < 4; ++i) af[i] = *(const bf16x8*)&As[p][(wm + i * 16 + lr) * 32 + lg * 8];
#pragma unroll
    for (int t = 0; t < 2; ++t) bfr[t] = *(const bf16x8*)&Bs[p][(wn + t * 16 + lr) * 32 + lg * 8];
#pragma unroll
    for (int i = 0; i < 4; ++i)
#pragma unroll
      for (int t = 0; t < 2; ++t)
        acc[i][t] = __builtin_amdgcn_mfma_f32_16x16x32_bf16(af[i], bfr[t], acc[i][t], 0, 0, 0);
  }
#pragma unroll
  for (int i = 0; i < 4; ++i) {
#pragma unroll
    for (int t = 0; t < 2; ++t) {
      int n = bn + wn + t * 16 + lr;
      float bv = bias[n];
#pragma unroll
      for (int r = 0; r < 4; ++r) {
        int row = bm + wm + i * 16 + lg * 4 + r;
        out[(size_t)row * D_MODEL + n] = acc[i][t][r] + bv;
      }
    }
  }
}

// ---------------- Flash attention round 9: 128-key supertiles, fixed V layout ----------------
// One combined softmax per 128 keys per strip. V staged as TWO 64x64 halves,
// each with the round-7-verified swizzle (store chunk c^ (row&7) via srow,
// read chunk (kh*4+quad)^(lr&7)) -- the round-8 failure was a store/read
// swizzle mismatch on a merged 64x128 V surface.
__global__ __launch_bounds__(256, 2) void k_attn9(const unsigned short* __restrict__ Qb,
                                                  const unsigned short* __restrict__ Kb,
                                                  const unsigned short* __restrict__ VT,
                                                  unsigned short* __restrict__ AO) {
  const int tid = threadIdx.x;
  const int wid = tid >> 6, lane = tid & 63;
  const int lr = lane & 15, quad = lane >> 4;
  const int blk = blockIdx.x;
  const int bh = blk & 31;                    // XCD pin: blk%8 == bh%8
  const int g = blk >> 5;                     // 0..15
  const int slot = (g < 8) ? g : 23 - g;      // CU pairing: slot a with 15-a
  const int b = bh >> 4, h = bh & 15;

  __shared__ __align__(16) unsigned short Ks[128 * 64];    // 128 keys x 64 d
  __shared__ __align__(16) unsigned short Vs[2][64 * 64];  // two 64d x 64s halves
  __shared__ __align__(16) unsigned short Pbuf[4][16 * 136];
  unsigned short* pb = &Pbuf[wid][0];

  const unsigned short* Kbh = Kb + (size_t)bh * S_LEN * HDIM;
  const unsigned short* VTbh = VT + (size_t)bh * HDIM * S_LEN;

  const int sL = slot * 4 + wid;              // 0..63
  const int Rs[2] = {sL * 16, (127 - sL) * 16};
  const int ntile = 32 - slot;                // 64-key tiles (block max)
  const int nsup = (ntile + 1) >> 1;          // 128-key supertiles

  bf16x8 qf[2][2];
#pragma unroll
  for (int st = 0; st < 2; ++st)
#pragma unroll
    for (int dh = 0; dh < 2; ++dh)
      qf[st][dh] = *(const bf16x8*)&Qb[((size_t)bh * S_LEN + Rs[st] + lr) * HDIM + dh * 32 + quad * 8];

  f32x4 Ot[2][4] = {};
  float ms[2] = {-1e30f, -1e30f};
  float ls[2] = {0.f, 0.f};

  const int srow = lane >> 3;                 // 0..7
  const int scol = ((lane & 7) ^ srow) * 8;   // xor-swizzled 16B chunk (8 chunks/row)

  for (int sp = 0; sp < nsup; ++sp) {
    const int k0 = sp * 128;
    __syncthreads();   // all waves done reading previous supertile
    // stage K: 128 rows x 8 chunks, 4 per thread (rows wid*32..wid*32+31)
#pragma unroll
    for (int j = 0; j < 4; ++j) {
      const int r0 = wid * 32 + j * 8;
      async_cp16(&Ks[r0 * 64 + lane * 8], &Kbh[(size_t)(k0 + r0 + srow) * HDIM + scol]);
    }
    // stage V^T halves: each 64 rows x 8 chunks, round-7 layout, 4 per thread total
#pragma unroll
    for (int hf = 0; hf < 2; ++hf)
#pragma unroll
      for (int j = 0; j < 2; ++j) {
        const int r0 = wid * 16 + j * 8;
        async_cp16(&Vs[hf][r0 * 64 + lane * 8],
                   &VTbh[(size_t)(r0 + srow) * S_LEN + k0 + hf * 64 + scol]);
      }
    __syncthreads();   // staged (drains vmcnt)

    // K fragments for all 128 keys (shared by both strips)
    bf16x8 kf[8][2];
#pragma unroll
    for (int kg = 0; kg < 8; ++kg)
#pragma unroll
      for (int dh = 0; dh < 2; ++dh)
        kf[kg][dh] = *(const bf16x8*)&Ks[(kg * 16 + lr) * 64 + (((dh * 4 + quad) ^ (lr & 7)) * 8)];

#pragma unroll
    for (int st = 0; st < 2; ++st) {
      const int R = Rs[st];
      if (k0 > R + 15) continue;              // strip finished (wave-uniform)
      const bool v1 = (k0 + 64 <= R + 15);    // second 64-key half needed?
      f32x4 Sv[8];
#pragma unroll
      for (int kg = 0; kg < 4; ++kg) {
        f32x4 a = {};
        a = __builtin_amdgcn_mfma_f32_16x16x32_bf16(kf[kg][0], qf[st][0], a, 0, 0, 0);
        a = __builtin_amdgcn_mfma_f32_16x16x32_bf16(kf[kg][1], qf[st][1], a, 0, 0, 0);
        Sv[kg] = a;
      }
      if (v1) {
#pragma unroll
        for (int kg = 4; kg < 8; ++kg) {
          f32x4 a = {};
          a = __builtin_amdgcn_mfma_f32_16x16x32_bf16(kf[kg][0], qf[st][0], a, 0, 0, 0);
          a = __builtin_amdgcn_mfma_f32_16x16x32_bf16(kf[kg][1], qf[st][1], a, 0, 0, 0);
          Sv[kg] = a;
        }
      }
      const int nkg = v1 ? 8 : 4;
      if (k0 + 127 > R) {                     // diagonal supertile: causal mask
        const int q = R + lr;
        for (int kg = 0; kg < nkg; ++kg)
#pragma unroll
          for (int r = 0; r < 4; ++r)
            if (k0 + kg * 16 + quad * 4 + r > q) Sv[kg][r] = -1e30f;
      }
      float mx = ms[st];
      for (int kg = 0; kg < nkg; ++kg)
        mx = fmaxf(mx, fmaxf(fmaxf(Sv[kg][0], Sv[kg][1]), fmaxf(Sv[kg][2], Sv[kg][3])));
      mx = fmaxf(mx, __shfl_xor(mx, 16));
      mx = fmaxf(mx, __shfl_xor(mx, 32));
      const float alpha = __builtin_amdgcn_exp2f(ms[st] - mx);
      ms[st] = mx;
      float rs = 0.f;
      for (int kg = 0; kg < nkg; ++kg) {
        float e0 = __builtin_amdgcn_exp2f(Sv[kg][0] - mx);
        float e1 = __builtin_amdgcn_exp2f(Sv[kg][1] - mx);
        float e2 = __builtin_amdgcn_exp2f(Sv[kg][2] - mx);
        float e3 = __builtin_amdgcn_exp2f(Sv[kg][3] - mx);
        rs += (e0 + e1) + (e2 + e3);
        *(unsigned int*)&pb[lr * 136 + kg * 16 + quad * 4]     = pkbf(e0, e1);
        *(unsigned int*)&pb[lr * 136 + kg * 16 + quad * 4 + 2] = pkbf(e2, e3);
      }
      rs += __shfl_xor(rs, 16);
      rs += __shfl_xor(rs, 32);
      ls[st] = ls[st] * alpha + rs;
#pragma unroll
      for (int dg = 0; dg < 4; ++dg)
#pragma unroll
        for (int r = 0; r < 4; ++r) Ot[st][dg][r] *= alpha;
      // PV per valid 64-key half: round-7-verified V read pattern
      for (int hf = 0; hf < (v1 ? 2 : 1); ++hf) {
        bf16x8 pf0 = *(const bf16x8*)&pb[lr * 136 + hf * 64 + quad * 8];
        bf16x8 pf1 = *(const bf16x8*)&pb[lr * 136 + hf * 64 + 32 + quad * 8];
#pragma unroll
        for (int dg = 0; dg < 4; ++dg) {
          const int vr = (dg * 16 + lr) * 64;
          bf16x8 vf0 = *(const bf16x8*)&Vs[hf][vr + ((quad ^ (lr & 7)) * 8)];
          bf16x8 vf1 = *(const bf16x8*)&Vs[hf][vr + (((4 + quad) ^ (lr & 7)) * 8)];
          Ot[st][dg] = __builtin_amdgcn_mfma_f32_16x16x32_bf16(vf0, pf0, Ot[st][dg], 0, 0, 0);
          Ot[st][dg] = __builtin_amdgcn_mfma_f32_16x16x32_bf16(vf1, pf1, Ot[st][dg], 0, 0, 0);
        }
      }
    }
  }

#pragma unroll
  for (int st = 0; st < 2; ++st) {
    const float rl = __builtin_amdgcn_rcpf(ls[st]);
    const int s = Rs[st] + lr;
#pragma unroll
    for (int dg = 0; dg < 4; ++dg) {
      const size_t o = ((size_t)b * S_LEN + s) * D_MODEL + h * 64 + dg * 16 + quad * 4;
      *(unsigned int*)&AO[o]     = pkbf(Ot[st][dg][0] * rl, Ot[st][dg][1] * rl);
      *(unsigned int*)&AO[o + 2] = pkbf(Ot[st][dg][2] * rl, Ot[st][dg][3] * rl);
    }
  }
}

extern "C" void kernel_launch(void* const* d_in, const int* in_sizes, int n_in,
                              void* d_out, int out_size, void* d_ws, size_t ws_size,
                              hipStream_t stream) {
  const float* x      = (const float*)d_in[0];
  const float* w_attn = (const float*)d_in[1];
  const float* b_attn = (const float*)d_in[2];
  const float* w_proj = (const float*)d_in[3];
  const float* b_proj = (const float*)d_in[4];
  float* out = (float*)d_out;

  unsigned short* ws     = (unsigned short*)d_ws;
  unsigned short* xb     = ws;                                   // 4096x1024
  unsigned short* wqkvT  = xb + (size_t)M_ROWS * D_MODEL;        // 3072x1024
  unsigned short* wprojT = wqkvT + (size_t)N_QKV * D_MODEL;      // 1024x1024
  unsigned short* Qb     = wprojT + (size_t)D_MODEL * D_MODEL;   // [B*H, S, hd] (pre-scaled)
  unsigned short* Kb     = Qb + (size_t)M_ROWS * D_MODEL;        // [B*H, S, hd]
  unsigned short* VT     = Kb + (size_t)M_ROWS * D_MODEL;        // [B*H, hd, S]
  unsigned short* AO     = xb;  // reuse: xb dead after QKV GEMM

  k_prep<<<8192, 256, 0, stream>>>(x, xb, w_attn, wqkvT, w_proj, wprojT);
  k_gemm_qkv<<<768, 256, 0, stream>>>(xb, wqkvT, b_attn, Qb, Kb, VT);
  k_attn9<<<512, 256, 0, stream>>>(Qb, Kb, VT, AO);
  k_gemm_proj<<<512, 256, 0, stream>>>(AO, wprojT, b_proj, out);
}